// Round 4
// baseline (188.531 us; speedup 1.0000x reference)
//
#include <hip/hip_runtime.h>
#include <hip/hip_bf16.h>
#include <math.h>

#define BB 2
#define SS 2048
#define DD 1024
#define HH 16
#define HDIM 64

typedef unsigned short u16;
typedef __attribute__((ext_vector_type(8))) short bfrag;   // 8 bf16 = 4 VGPRs
typedef __attribute__((ext_vector_type(4))) short s16x4;   // 4 bf16 = 2 VGPRs
typedef __attribute__((ext_vector_type(4))) float f32x4;

#define NEG_BIG (-1e30f)
// 1/sqrt(64) * log2(e): folded into Q so attention uses exp2 directly
#define QSCALE 0.18033688011112042f

__device__ __forceinline__ u16 f2u(float f) {
    unsigned int u = __builtin_bit_cast(unsigned int, f);
    u += 0x7fffu + ((u >> 16) & 1u);
    return (u16)(u >> 16);
}

__device__ __forceinline__ void async16(const u16* g, u16* l) {
    __builtin_amdgcn_global_load_lds((__attribute__((address_space(1))) void*)g,
                                     (__attribute__((address_space(3))) void*)l,
                                     16, 0, 0);
}

__device__ __forceinline__ f32x4 mfma16(bfrag a, bfrag b, f32x4 c) {
    return __builtin_amdgcn_mfma_f32_16x16x32_bf16(a, b, c, 0, 0, 0);
}

// 16x16x16 bf16 MFMA: builtin name differs across ROCm; dispatch at compile time.
__device__ __forceinline__ f32x4 mfma_pv(s16x4 a, s16x4 b, f32x4 c) {
#if __has_builtin(__builtin_amdgcn_mfma_f32_16x16x16_bf16)
    return __builtin_amdgcn_mfma_f32_16x16x16_bf16(a, b, c, 0, 0, 0);
#elif __has_builtin(__builtin_amdgcn_mfma_f32_16x16x16bf16_1k)
    return __builtin_amdgcn_mfma_f32_16x16x16bf16_1k(a, b, c, 0, 0, 0);
#else
    f32x4 d;
    asm("v_mfma_f32_16x16x16_bf16 %0, %1, %2, %3" : "=v"(d) : "v"(a), "v"(b), "v"(c));
    return d;
#endif
}

// ---------------------------------------------------------------------------
// prep: fused cvt_x + cvt_wT (unchanged).
// ---------------------------------------------------------------------------
__global__ __launch_bounds__(256) void prep_k(
    const float* __restrict__ x,  u16* __restrict__ xb,
    const float* __restrict__ wq, const float* __restrict__ wk,
    const float* __restrict__ wv, const float* __restrict__ wo,
    u16* __restrict__ wT)
{
    const int id = blockIdx.x;
    const int t = threadIdx.x;
    if (id < 2048) {
        int i = (id * 256 + t) * 8;
        float4 a = *(const float4*)(x + i);
        float4 b = *(const float4*)(x + i + 4);
        u16 o[8] = { f2u(a.x), f2u(a.y), f2u(a.z), f2u(a.w),
                     f2u(b.x), f2u(b.y), f2u(b.z), f2u(b.w) };
        *(uint4*)(xb + i) = *(uint4*)o;
        return;
    }
    const int wid = id - 2048;
    const int z = wid >> 8;
    const int kt = wid & 15, nt = (wid >> 4) & 15;
    const float* w = (z == 0) ? wq : (z == 1) ? wk : (z == 2) ? wv : wo;
    u16* o = wT + (size_t)z * DD * DD;
    __shared__ __align__(16) u16 T[64][72];
    const int k0 = kt * 64, n0 = nt * 64;
    {
        int kr = t >> 2, nb = (t & 3) * 16;
        const float4* s4 = (const float4*)(w + (size_t)(k0 + kr) * DD + n0 + nb);
        #pragma unroll
        for (int jj = 0; jj < 4; ++jj) {
            float4 v = s4[jj];
            T[kr][nb + jj*4 + 0] = f2u(v.x);
            T[kr][nb + jj*4 + 1] = f2u(v.y);
            T[kr][nb + jj*4 + 2] = f2u(v.z);
            T[kr][nb + jj*4 + 3] = f2u(v.w);
        }
    }
    __syncthreads();
    {
        int nr = t >> 2, kb = (t & 3) * 16;
        u16 tmp[16];
        #pragma unroll
        for (int j = 0; j < 16; ++j) tmp[j] = T[kb + j][nr];
        *(uint4*)(o + (size_t)(n0 + nr) * DD + k0 + kb)     = ((uint4*)tmp)[0];
        *(uint4*)(o + (size_t)(n0 + nr) * DD + k0 + kb + 8) = ((uint4*)tmp)[1];
    }
}

// ===========================================================================
// QKV GEMM — m97-verified 128x128 tile: BM=128, BN=128, BK=64, acc[4][4],
// 32 MFMA per barrier-pair -> grid (32, 8, 3) = 768 blocks.
// ===========================================================================
__global__ __launch_bounds__(256) void gemm_qkv_k(
    const u16* __restrict__ xb, const u16* __restrict__ wT,
    u16* __restrict__ Qo, u16* __restrict__ Ko, u16* __restrict__ Vt)
{
    const u16* wTz = wT + (size_t)blockIdx.z * DD * DD;
    const float osc = (blockIdx.z == 0) ? QSCALE : 1.0f;

    __shared__ __align__(16) u16 As[128 * 64];   // 16 KB
    __shared__ __align__(16) u16 Bs[128 * 64];   // 16 KB

    const int t = threadIdx.x;
    const int m0 = blockIdx.x * 128, n0 = blockIdx.y * 128;
    const int lane15 = t & 15, quad = (t >> 4) & 3, wave = t >> 6;
    const int wm = wave & 1, wn = wave >> 1;

    int grow[4], gcol[4];
    #pragma unroll
    for (int i = 0; i < 4; ++i) {
        int c = t + i * 256;
        grow[i] = c >> 3;
        gcol[i] = (c & 7) ^ (grow[i] & 7);
    }
    const int ldb = (t & 192) * 8;

    int aoff[4][2], boff[4][2];
    #pragma unroll
    for (int mi = 0; mi < 4; ++mi) {
        int r = wm * 64 + mi * 16 + lane15;
        #pragma unroll
        for (int kh = 0; kh < 2; ++kh)
            aoff[mi][kh] = (r * 8 + ((kh * 4 + quad) ^ (r & 7))) * 8;
    }
    #pragma unroll
    for (int ni = 0; ni < 4; ++ni) {
        int r = wn * 64 + ni * 16 + lane15;
        #pragma unroll
        for (int kh = 0; kh < 2; ++kh)
            boff[ni][kh] = (r * 8 + ((kh * 4 + quad) ^ (r & 7))) * 8;
    }

    f32x4 acc[4][4];
    #pragma unroll
    for (int mi = 0; mi < 4; ++mi)
        #pragma unroll
        for (int ni = 0; ni < 4; ++ni)
            acc[mi][ni] = (f32x4){0.f, 0.f, 0.f, 0.f};

    for (int it = 0; it < 16; ++it) {
        const int k0 = it * 64;
        #pragma unroll
        for (int i = 0; i < 4; ++i) {
            async16(xb  + (size_t)(m0 + grow[i]) * DD + k0 + gcol[i] * 8,
                    As + ldb + i * 2048);
            async16(wTz + (size_t)(n0 + grow[i]) * DD + k0 + gcol[i] * 8,
                    Bs + ldb + i * 2048);
        }
        __syncthreads();
        #pragma unroll
        for (int kh = 0; kh < 2; ++kh) {
            bfrag av[4], bv[4];
            #pragma unroll
            for (int mi = 0; mi < 4; ++mi) av[mi] = *(const bfrag*)(As + aoff[mi][kh]);
            #pragma unroll
            for (int ni = 0; ni < 4; ++ni) bv[ni] = *(const bfrag*)(Bs + boff[ni][kh]);
            #pragma unroll
            for (int mi = 0; mi < 4; ++mi)
                #pragma unroll
                for (int ni = 0; ni < 4; ++ni)
                    acc[mi][ni] = mfma16(av[mi], bv[ni], acc[mi][ni]);
        }
        __syncthreads();
    }

    const int bq = m0 >> 11;
    const int ms = m0 & (SS - 1);
    const int h0 = n0 >> 6;

    if (blockIdx.z != 2) {
        u16* out = (blockIdx.z == 0) ? Qo : Ko;
        const int h = h0 + wn;              // this wave's head (BN half)
        u16* dst = out + (((size_t)(bq * HH + h)) * SS) * HDIM;
        #pragma unroll
        for (int mi = 0; mi < 4; ++mi) {
            #pragma unroll
            for (int r = 0; r < 4; ++r) {
                int s = ms + wm * 64 + mi * 16 + quad * 4 + r;
                #pragma unroll
                for (int ni = 0; ni < 4; ++ni) {
                    int hd = ni * 16 + lane15;
                    dst[(size_t)s * HDIM + hd] = f2u(acc[mi][ni][r] * osc);
                }
            }
        }
    } else {
        // V transpose epilogue at BN=128: T[nl][ml], nl<64 -> As, nl>=64 -> Bs
        __syncthreads();
        #pragma unroll
        for (int mi = 0; mi < 4; ++mi)
            #pragma unroll
            for (int r = 0; r < 4; ++r) {
                int ml = wm * 64 + mi * 16 + quad * 4 + r;
                #pragma unroll
                for (int ni = 0; ni < 4; ++ni) {
                    int nl = wn * 64 + ni * 16 + lane15;
                    u16* T = (nl < 64) ? As : Bs;
                    T[(nl & 63) * 128 + (ml ^ ((nl & 7) << 4))] = f2u(acc[mi][ni][r]);
                }
            }
        __syncthreads();
        #pragma unroll
        for (int i = 0; i < 8; ++i) {
            int c = t + i * 256;
            int row = c >> 4;                 // nl 0..127
            int mb  = (c & 15) * 8;           // ml chunk base
            const u16* T = (row < 64) ? As : Bs;
            uint4 val = *(const uint4*)&T[(row & 63) * 128 + (mb ^ ((row & 7) << 4))];
            int h = h0 + (row >> 6);
            u16* dst = Vt + ((size_t)(bq * HH + h)) * (HDIM * SS)
                          + (size_t)(row & 63) * SS + ms + mb;
            *(uint4*)dst = val;
        }
    }
}

// ---------------------------------------------------------------------------
// Out projection — same m97 skeleton: BM=128, BN=128, BK=64 -> grid (32, 8).
// Fused bias, fp32 out.
// ---------------------------------------------------------------------------
__global__ __launch_bounds__(256) void gemm_out_k(
    const u16* __restrict__ ctxb, const u16* __restrict__ woT,
    const float* __restrict__ bo, float* __restrict__ out)
{
    __shared__ __align__(16) u16 As[128 * 64];   // 16 KB
    __shared__ __align__(16) u16 Bs[128 * 64];   // 16 KB

    const int t = threadIdx.x;
    const int m0 = blockIdx.x * 128, n0 = blockIdx.y * 128;
    const int lane15 = t & 15, quad = (t >> 4) & 3, wave = t >> 6;
    const int wm = wave & 1, wn = wave >> 1;

    int grow[4], gcol[4];
    #pragma unroll
    for (int i = 0; i < 4; ++i) {
        int c = t + i * 256;
        grow[i] = c >> 3;
        gcol[i] = (c & 7) ^ (grow[i] & 7);
    }
    const int ldb = (t & 192) * 8;

    int aoff[4][2], boff[4][2];
    #pragma unroll
    for (int mi = 0; mi < 4; ++mi) {
        int r = wm * 64 + mi * 16 + lane15;
        #pragma unroll
        for (int kh = 0; kh < 2; ++kh)
            aoff[mi][kh] = (r * 8 + ((kh * 4 + quad) ^ (r & 7))) * 8;
    }
    #pragma unroll
    for (int ni = 0; ni < 4; ++ni) {
        int r = wn * 64 + ni * 16 + lane15;
        #pragma unroll
        for (int kh = 0; kh < 2; ++kh)
            boff[ni][kh] = (r * 8 + ((kh * 4 + quad) ^ (r & 7))) * 8;
    }

    f32x4 acc[4][4];
    #pragma unroll
    for (int mi = 0; mi < 4; ++mi)
        #pragma unroll
        for (int ni = 0; ni < 4; ++ni)
            acc[mi][ni] = (f32x4){0.f, 0.f, 0.f, 0.f};

    for (int it = 0; it < 16; ++it) {
        const int k0 = it * 64;
        #pragma unroll
        for (int i = 0; i < 4; ++i) {
            async16(ctxb + (size_t)(m0 + grow[i]) * DD + k0 + gcol[i] * 8,
                    As + ldb + i * 2048);
            async16(woT  + (size_t)(n0 + grow[i]) * DD + k0 + gcol[i] * 8,
                    Bs + ldb + i * 2048);
        }
        __syncthreads();
        #pragma unroll
        for (int kh = 0; kh < 2; ++kh) {
            bfrag av[4], bv[4];
            #pragma unroll
            for (int mi = 0; mi < 4; ++mi) av[mi] = *(const bfrag*)(As + aoff[mi][kh]);
            #pragma unroll
            for (int ni = 0; ni < 4; ++ni) bv[ni] = *(const bfrag*)(Bs + boff[ni][kh]);
            #pragma unroll
            for (int mi = 0; mi < 4; ++mi)
                #pragma unroll
                for (int ni = 0; ni < 4; ++ni)
                    acc[mi][ni] = mfma16(av[mi], bv[ni], acc[mi][ni]);
        }
        __syncthreads();
    }

    float bias[4];
    #pragma unroll
    for (int ni = 0; ni < 4; ++ni)
        bias[ni] = bo[n0 + wn * 64 + ni * 16 + lane15];

    #pragma unroll
    for (int mi = 0; mi < 4; ++mi) {
        #pragma unroll
        for (int r = 0; r < 4; ++r) {
            int m = m0 + wm * 64 + mi * 16 + quad * 4 + r;
            #pragma unroll
            for (int ni = 0; ni < 4; ++ni) {
                int n = n0 + wn * 64 + ni * 16 + lane15;
                out[(size_t)m * DD + n] = acc[mi][ni][r] + bias[ni];
            }
        }
    }
}

// ===========================================================================
// MFMA flash attention — round-2 version (best measured: 46.3 us).
// Swapped-operand structure; V read as b128 broadcast + half-select;
// V frags double-buffered in regs; balanced qt remap; grid (32, 32).
// ===========================================================================
struct AttnState {
    f32x4 acc_o[4];
    f32x4 acc_s;
};

template<bool MASKED>
__device__ __forceinline__ void qkt_pv(
    const u16* __restrict__ Kc, const u16* __restrict__ Vc,
    const bfrag bq[2], const int koff[2], const int voffb[4],
    bool qhi, int kv0, int qg, int quad4,
    AttnState& st, s16x4 ones4)
{
    f32x4 sT[4];
    #pragma unroll
    for (int ni = 0; ni < 4; ++ni) sT[ni] = (f32x4){0.f, 0.f, 0.f, 0.f};

    // V frags for ni=0 issued before the MFMA cluster: latency hides under QK^T
    bfrag vv[2][4];
    #pragma unroll
    for (int nd = 0; nd < 4; ++nd)
        vv[0][nd] = *(const bfrag*)&Vc[voffb[0] + nd * 1024];

    __builtin_amdgcn_s_setprio(1);
    #pragma unroll
    for (int kh = 0; kh < 2; ++kh)
        #pragma unroll
        for (int ni = 0; ni < 4; ++ni)
            sT[ni] = mfma16(*(const bfrag*)&Kc[koff[kh] + ni * 1024], bq[kh], sT[ni]);
    __builtin_amdgcn_s_setprio(0);

    #pragma unroll
    for (int ni = 0; ni < 4; ++ni) {
        if (ni < 3) {
            #pragma unroll
            for (int nd = 0; nd < 4; ++nd)
                vv[(ni + 1) & 1][nd] = *(const bfrag*)&Vc[voffb[ni + 1] + nd * 1024];
        }
        float pv[4];
        #pragma unroll
        for (int r = 0; r < 4; ++r) {
            float v = sT[ni][r];
            if (MASKED) {
                int kvg = kv0 + ni * 16 + quad4 + r;
                if (kvg > qg) v = NEG_BIG;
            }
            pv[r] = exp2f(v);
        }
        unsigned lo = __builtin_amdgcn_perm(
            __builtin_bit_cast(unsigned, pv[1]),
            __builtin_bit_cast(unsigned, pv[0]), 0x07060302u);
        unsigned hi = __builtin_amdgcn_perm(
            __builtin_bit_cast(unsigned, pv[3]),
            __builtin_bit_cast(unsigned, pv[2]), 0x07060302u);
        s16x4 pf = __builtin_bit_cast(s16x4,
            ((unsigned long long)hi << 32) | (unsigned long long)lo);
        __builtin_amdgcn_s_setprio(1);
        st.acc_s = mfma_pv(ones4, pf, st.acc_s);
        #pragma unroll
        for (int nd = 0; nd < 4; ++nd) {
            bfrag v8 = vv[ni & 1][nd];
            s16x4 vlo = __builtin_shufflevector(v8, v8, 0, 1, 2, 3);
            s16x4 vhi = __builtin_shufflevector(v8, v8, 4, 5, 6, 7);
            s16x4 va = qhi ? vhi : vlo;
            st.acc_o[nd] = mfma_pv(va, pf, st.acc_o[nd]);
        }
        __builtin_amdgcn_s_setprio(0);
    }
}

__global__ __launch_bounds__(256, 4) void attn_k(
    const u16* __restrict__ Q, const u16* __restrict__ K,
    const u16* __restrict__ Vt, u16* __restrict__ ctx)
{
    __shared__ __align__(16) u16 Ks[2][64 * 64];   // 16 KB
    __shared__ __align__(16) u16 Vs[2][64 * 64];   // 16 KB
    const int t = threadIdx.x;
    const int lane15 = t & 15, quad = (t >> 4) & 3, wave = t >> 6;
    const int bh = blockIdx.x;
    // balanced causal mapping: dispatch rounds (y&7 fixed) get qt
    // {31-y0, y0, 23-y0, 8+y0} -> per-CU work sum is constant.
    const int yy = (int)blockIdx.y;
    const int y0 = yy & 7, rnd = yy >> 3;
    const int qt = (rnd == 0) ? 31 - y0 : (rnd == 1) ? y0
                 : (rnd == 2) ? 23 - y0 : 8 + y0;
    const int q0 = qt * 64;
    const int b = bh >> 4, h = bh & 15;
    const u16* Qb = Q  + (size_t)bh * SS * HDIM;
    const u16* Kb = K  + (size_t)bh * SS * HDIM;
    const u16* Vb = Vt + (size_t)bh * HDIM * SS;

    // staging map (same swizzle as before)
    const int kr0 = t >> 3,         ks0 = t & 7;
    const int kr1 = (t + 256) >> 3, ks1 = (t + 256) & 7;
    const int kc0 = ks0 ^ (kr0 & 7);
    const int kc1 = ks1 ^ (kr1 & 7);
    const int ldst = (t & 192) * 8;

    // Q staged temporarily into Ks[1] (consumed into regs before kt=0 prefetch)
    async16(Qb + (size_t)(q0 + kr0) * HDIM + kc0 * 8, &Ks[1][ldst]);
    async16(Qb + (size_t)(q0 + kr1) * HDIM + kc1 * 8, &Ks[1][ldst + 2048]);
    async16(Kb + (size_t)kr0 * HDIM + kc0 * 8, &Ks[0][ldst]);
    async16(Kb + (size_t)kr1 * HDIM + kc1 * 8, &Ks[0][ldst + 2048]);
    async16(Vb + (size_t)kr0 * SS + kc0 * 8, &Vs[0][ldst]);
    async16(Vb + (size_t)kr1 * SS + kc1 * 8, &Vs[0][ldst + 2048]);

    const int r7 = lane15 & 7;
    // K fragment offsets (row = ni*16+lane15; row&7 == lane15&7): +ni*1024 u16
    int koff[2];
    #pragma unroll
    for (int kh = 0; kh < 2; ++kh)
        koff[kh] = (lane15 * 8 + ((kh * 4 + quad) ^ r7)) * 8;
    // V^T b128 fragment offsets: full 16B slot (ni*2 + (quad>>1)) ^ r7;
    // quad pairs share addresses (broadcast); (quad&1) half selected in VALU.
    int voffb[4];
    #pragma unroll
    for (int ni = 0; ni < 4; ++ni)
        voffb[ni] = (lane15 * 8 + ((ni * 2 + (quad >> 1)) ^ r7)) * 8;
    const bool qhi = (quad & 1) != 0;

    __syncthreads();
    bfrag bq[2];
    bq[0] = *(const bfrag*)&Ks[1][koff[0] + wave * 1024];
    bq[1] = *(const bfrag*)&Ks[1][koff[1] + wave * 1024];
    __syncthreads();   // Q reads done before kt=1 prefetch overwrites Ks[1]

    s16x4 ones4;
    #pragma unroll
    for (int i = 0; i < 4; ++i) ones4[i] = (short)0x3f80;   // bf16 1.0

    AttnState st;
    st.acc_s = (f32x4){0.f, 0.f, 0.f, 0.f};
    #pragma unroll
    for (int nd = 0; nd < 4; ++nd) st.acc_o[nd] = (f32x4){0.f, 0.f, 0.f, 0.f};

    const int qg = q0 + wave * 16 + lane15;   // this lane's absolute q row
    const int quad4 = quad * 4;

    // off-diagonal tiles: no masking code at all
    for (int kt = 0; kt < qt; ++kt) {
        const int nv0 = (kt + 1) * 64;
        const int pb = (kt + 1) & 1;
        async16(Kb + (size_t)(nv0 + kr0) * HDIM + kc0 * 8, &Ks[pb][ldst]);
        async16(Kb + (size_t)(nv0 + kr1) * HDIM + kc1 * 8, &Ks[pb][ldst + 2048]);
        async16(Vb + (size_t)kr0 * SS + nv0 + kc0 * 8, &Vs[pb][ldst]);
        async16(Vb + (size_t)kr1 * SS + nv0 + kc1 * 8, &Vs[pb][ldst + 2048]);
        qkt_pv<false>(Ks[kt & 1], Vs[kt & 1], bq, koff, voffb,
                      qhi, kt * 64, qg, quad4, st, ones4);
        __syncthreads();
    }
    // diagonal tile (no prefetch, masked)
    qkt_pv<true>(Ks[qt & 1], Vs[qt & 1], bq, koff, voffb,
                 qhi, qt * 64, qg, quad4, st, ones4);

    // epilogue: each lane owns one q row; acc_s rows are replicated row-sums
    const float inv = 1.f / st.acc_s[0];
    const int srow = q0 + wave * 16 + lane15;
    u16* dst = ctx + ((size_t)b * SS + srow) * DD + h * HDIM + quad4;
    #pragma unroll
    for (int nd = 0; nd < 4; ++nd) {
        uint2 stw;
        stw.x = (unsigned)f2u(st.acc_o[nd][0] * inv) |
                ((unsigned)f2u(st.acc_o[nd][1] * inv) << 16);
        stw.y = (unsigned)f2u(st.acc_o[nd][2] * inv) |
                ((unsigned)f2u(st.acc_o[nd][3] * inv) << 16);
        *(uint2*)(dst + nd * 16) = stw;
    }
}

extern "C" void kernel_launch(void* const* d_in, const int* in_sizes, int n_in,
                              void* d_out, int out_size, void* d_ws, size_t ws_size,
                              hipStream_t stream) {
    const float* x  = (const float*)d_in[0];
    const float* wq = (const float*)d_in[1];
    const float* wk = (const float*)d_in[2];
    const float* wv = (const float*)d_in[3];
    const float* wo = (const float*)d_in[4];
    const float* bo = (const float*)d_in[5];
    float* out = (float*)d_out;

    char* ws = (char*)d_ws;
    const size_t MB8 = (size_t)8 * 1024 * 1024;
    u16* xb  = (u16*)(ws);             // 8MB; ctx reuses after qkv consumption
    u16* wT  = (u16*)(ws + MB8);       // 8MB
    u16* Qb  = (u16*)(ws + 2 * MB8);   // 8MB
    u16* Kb  = (u16*)(ws + 3 * MB8);   // 8MB
    u16* Vt  = (u16*)(ws + 4 * MB8);   // 8MB
    u16* ctxb = xb;

    prep_k    <<<3072, 256, 0, stream>>>(x, xb, wq, wk, wv, wo, wT);
    gemm_qkv_k<<<dim3(32, 8, 3), 256, 0, stream>>>(xb, wT, Qb, Kb, Vt);
    attn_k    <<<dim3(32, 32), 256, 0, stream>>>(Qb, Kb, Vt, ctxb);
    gemm_out_k<<<dim3(32, 8), 256, 0, stream>>>(ctxb, wT + (size_t)3 * DD * DD, bo, out);
}

// Round 5
// 181.752 us; speedup vs baseline: 1.0373x; 1.0373x over previous
//
#include <hip/hip_runtime.h>
#include <hip/hip_bf16.h>
#include <math.h>

#define BB 2
#define SS 2048
#define DD 1024
#define HH 16
#define HDIM 64

typedef unsigned short u16;
typedef __attribute__((ext_vector_type(8))) short bfrag;   // 8 bf16 = 4 VGPRs
typedef __attribute__((ext_vector_type(4))) short s16x4;   // 4 bf16 = 2 VGPRs
typedef __attribute__((ext_vector_type(4))) float f32x4;

#define NEG_BIG (-1e30f)
// 1/sqrt(64) * log2(e): folded into Q so attention uses exp2 directly
#define QSCALE 0.18033688011112042f

__device__ __forceinline__ u16 f2u(float f) {
    unsigned int u = __builtin_bit_cast(unsigned int, f);
    u += 0x7fffu + ((u >> 16) & 1u);
    return (u16)(u >> 16);
}

__device__ __forceinline__ void async16(const u16* g, u16* l) {
    __builtin_amdgcn_global_load_lds((__attribute__((address_space(1))) void*)g,
                                     (__attribute__((address_space(3))) void*)l,
                                     16, 0, 0);
}

__device__ __forceinline__ f32x4 mfma16(bfrag a, bfrag b, f32x4 c) {
    return __builtin_amdgcn_mfma_f32_16x16x32_bf16(a, b, c, 0, 0, 0);
}

// 16x16x16 bf16 MFMA: builtin name differs across ROCm; dispatch at compile time.
__device__ __forceinline__ f32x4 mfma_pv(s16x4 a, s16x4 b, f32x4 c) {
#if __has_builtin(__builtin_amdgcn_mfma_f32_16x16x16_bf16)
    return __builtin_amdgcn_mfma_f32_16x16x16_bf16(a, b, c, 0, 0, 0);
#elif __has_builtin(__builtin_amdgcn_mfma_f32_16x16x16bf16_1k)
    return __builtin_amdgcn_mfma_f32_16x16x16bf16_1k(a, b, c, 0, 0, 0);
#else
    f32x4 d;
    asm("v_mfma_f32_16x16x16_bf16 %0, %1, %2, %3" : "=v"(d) : "v"(a), "v"(b), "v"(c));
    return d;
#endif
}

// ---------------------------------------------------------------------------
// prep: fused cvt_x + cvt_wT (round-0 verbatim).
// ---------------------------------------------------------------------------
__global__ __launch_bounds__(256) void prep_k(
    const float* __restrict__ x,  u16* __restrict__ xb,
    const float* __restrict__ wq, const float* __restrict__ wk,
    const float* __restrict__ wv, const float* __restrict__ wo,
    u16* __restrict__ wT)
{
    const int id = blockIdx.x;
    const int t = threadIdx.x;
    if (id < 2048) {
        int i = (id * 256 + t) * 8;
        float4 a = *(const float4*)(x + i);
        float4 b = *(const float4*)(x + i + 4);
        u16 o[8] = { f2u(a.x), f2u(a.y), f2u(a.z), f2u(a.w),
                     f2u(b.x), f2u(b.y), f2u(b.z), f2u(b.w) };
        *(uint4*)(xb + i) = *(uint4*)o;
        return;
    }
    const int wid = id - 2048;
    const int z = wid >> 8;
    const int kt = wid & 15, nt = (wid >> 4) & 15;
    const float* w = (z == 0) ? wq : (z == 1) ? wk : (z == 2) ? wv : wo;
    u16* o = wT + (size_t)z * DD * DD;
    __shared__ __align__(16) u16 T[64][72];
    const int k0 = kt * 64, n0 = nt * 64;
    {
        int kr = t >> 2, nb = (t & 3) * 16;
        const float4* s4 = (const float4*)(w + (size_t)(k0 + kr) * DD + n0 + nb);
        #pragma unroll
        for (int jj = 0; jj < 4; ++jj) {
            float4 v = s4[jj];
            T[kr][nb + jj*4 + 0] = f2u(v.x);
            T[kr][nb + jj*4 + 1] = f2u(v.y);
            T[kr][nb + jj*4 + 2] = f2u(v.z);
            T[kr][nb + jj*4 + 3] = f2u(v.w);
        }
    }
    __syncthreads();
    {
        int nr = t >> 2, kb = (t & 3) * 16;
        u16 tmp[16];
        #pragma unroll
        for (int j = 0; j < 16; ++j) tmp[j] = T[kb + j][nr];
        *(uint4*)(o + (size_t)(n0 + nr) * DD + k0 + kb)     = ((uint4*)tmp)[0];
        *(uint4*)(o + (size_t)(n0 + nr) * DD + k0 + kb + 8) = ((uint4*)tmp)[1];
    }
}

// ===========================================================================
// QKV GEMM (round-0 verbatim): BM=128, BN=64, BK=64 -> 1536 blocks.
// ===========================================================================
__global__ __launch_bounds__(256) void gemm_qkv_k(
    const u16* __restrict__ xb, const u16* __restrict__ wT,
    u16* __restrict__ Qo, u16* __restrict__ Ko, u16* __restrict__ Vt)
{
    const u16* wTz = wT + (size_t)blockIdx.z * DD * DD;
    const float osc = (blockIdx.z == 0) ? QSCALE : 1.0f;

    __shared__ __align__(16) u16 As[128 * 64];   // 16 KB
    __shared__ __align__(16) u16 Bs[64 * 64];    // 8 KB

    const int t = threadIdx.x;
    const int m0 = blockIdx.x * 128, n0 = blockIdx.y * 64;
    const int lane15 = t & 15, quad = (t >> 4) & 3, wave = t >> 6;
    const int wm = wave & 1, wn = wave >> 1;

    int arow[4], acol[4];
    #pragma unroll
    for (int i = 0; i < 4; ++i) {
        int c = t + i * 256;
        arow[i] = c >> 3;
        acol[i] = (c & 7) ^ (arow[i] & 7);
    }
    const int br0 = t >> 3,         bs0 = t & 7;
    const int br1 = (t + 256) >> 3, bs1 = (t + 256) & 7;
    const int bc0 = bs0 ^ (br0 & 7);
    const int bc1 = bs1 ^ (br1 & 7);
    const int ldb = (t & 192) * 8;

    int aoff[4][2], boff[2][2];
    #pragma unroll
    for (int mi = 0; mi < 4; ++mi) {
        int r = wm * 64 + mi * 16 + lane15;
        #pragma unroll
        for (int kh = 0; kh < 2; ++kh)
            aoff[mi][kh] = (r * 8 + ((kh * 4 + quad) ^ (r & 7))) * 8;
    }
    #pragma unroll
    for (int ni = 0; ni < 2; ++ni) {
        int r = wn * 32 + ni * 16 + lane15;
        #pragma unroll
        for (int kh = 0; kh < 2; ++kh)
            boff[ni][kh] = (r * 8 + ((kh * 4 + quad) ^ (r & 7))) * 8;
    }

    f32x4 acc[4][2];
    #pragma unroll
    for (int mi = 0; mi < 4; ++mi)
        #pragma unroll
        for (int ni = 0; ni < 2; ++ni)
            acc[mi][ni] = (f32x4){0.f, 0.f, 0.f, 0.f};

    for (int it = 0; it < 16; ++it) {
        const int k0 = it * 64;
        #pragma unroll
        for (int i = 0; i < 4; ++i)
            async16(xb + (size_t)(m0 + arow[i]) * DD + k0 + acol[i] * 8,
                    As + ldb + i * 2048);
        async16(wTz + (size_t)(n0 + br0) * DD + k0 + bc0 * 8, Bs + ldb);
        async16(wTz + (size_t)(n0 + br1) * DD + k0 + bc1 * 8, Bs + ldb + 2048);
        __syncthreads();
        #pragma unroll
        for (int kh = 0; kh < 2; ++kh) {
            bfrag av[4], bv[2];
            #pragma unroll
            for (int mi = 0; mi < 4; ++mi) av[mi] = *(const bfrag*)(As + aoff[mi][kh]);
            #pragma unroll
            for (int ni = 0; ni < 2; ++ni) bv[ni] = *(const bfrag*)(Bs + boff[ni][kh]);
            #pragma unroll
            for (int mi = 0; mi < 4; ++mi)
                #pragma unroll
                for (int ni = 0; ni < 2; ++ni)
                    acc[mi][ni] = mfma16(av[mi], bv[ni], acc[mi][ni]);
        }
        __syncthreads();
    }

    const int h = n0 >> 6;
    const int bq = m0 >> 11;
    const int ms = m0 & (SS - 1);

    if (blockIdx.z != 2) {
        u16* out = (blockIdx.z == 0) ? Qo : Ko;
        u16* dst = out + (((size_t)(bq * HH + h)) * SS) * HDIM;
        #pragma unroll
        for (int mi = 0; mi < 4; ++mi) {
            #pragma unroll
            for (int r = 0; r < 4; ++r) {
                int s = ms + wm * 64 + mi * 16 + quad * 4 + r;
                #pragma unroll
                for (int ni = 0; ni < 2; ++ni) {
                    int hd = wn * 32 + ni * 16 + lane15;
                    dst[(size_t)s * HDIM + hd] = f2u(acc[mi][ni][r] * osc);
                }
            }
        }
    } else {
        u16* T = As;
        __syncthreads();
        #pragma unroll
        for (int mi = 0; mi < 4; ++mi)
            #pragma unroll
            for (int r = 0; r < 4; ++r) {
                int ml = wm * 64 + mi * 16 + quad * 4 + r;
                #pragma unroll
                for (int ni = 0; ni < 2; ++ni) {
                    int nl = wn * 32 + ni * 16 + lane15;
                    T[nl * 128 + (ml ^ ((nl & 7) << 4))] = f2u(acc[mi][ni][r]);
                }
            }
        __syncthreads();
        u16* dst = Vt + ((size_t)(bq * HH + h)) * (HDIM * SS);
        #pragma unroll
        for (int i = 0; i < 4; ++i) {
            int c = t + i * 256;
            int row = c >> 4;
            int mb  = (c & 15) * 8;
            uint4 val = *(const uint4*)&T[row * 128 + (mb ^ ((row & 7) << 4))];
            *(uint4*)(dst + (size_t)row * SS + ms + mb) = val;
        }
    }
}

// ---------------------------------------------------------------------------
// Out projection (round-0 verbatim): BM=64, BN=64, BK=128 -> grid (64,16).
// ---------------------------------------------------------------------------
__global__ __launch_bounds__(256) void gemm_out_k(
    const u16* __restrict__ ctxb, const u16* __restrict__ woT,
    const float* __restrict__ bo, float* __restrict__ out)
{
    __shared__ __align__(16) u16 As[2][4096];    // [k-half][64x64]
    __shared__ __align__(16) u16 Bs[2][4096];

    const int t = threadIdx.x;
    const int m0 = blockIdx.x * 64, n0 = blockIdx.y * 64;
    const int lane15 = t & 15, quad = (t >> 4) & 3, wave = t >> 6;
    const int wm = wave & 1, wn = wave >> 1;

    const int br0 = t >> 3,         bs0 = t & 7;
    const int br1 = (t + 256) >> 3, bs1 = (t + 256) & 7;
    const int bc0 = bs0 ^ (br0 & 7);
    const int bc1 = bs1 ^ (br1 & 7);
    const int ldb = (t & 192) * 8;

    int aoff[2][2], boff[2][2];
    #pragma unroll
    for (int mi = 0; mi < 2; ++mi) {
        int r = wm * 32 + mi * 16 + lane15;
        #pragma unroll
        for (int kh = 0; kh < 2; ++kh)
            aoff[mi][kh] = (r * 8 + ((kh * 4 + quad) ^ (r & 7))) * 8;
    }
    #pragma unroll
    for (int ni = 0; ni < 2; ++ni) {
        int r = wn * 32 + ni * 16 + lane15;
        #pragma unroll
        for (int kh = 0; kh < 2; ++kh)
            boff[ni][kh] = (r * 8 + ((kh * 4 + quad) ^ (r & 7))) * 8;
    }

    f32x4 acc[2][2];
    #pragma unroll
    for (int mi = 0; mi < 2; ++mi)
        #pragma unroll
        for (int ni = 0; ni < 2; ++ni)
            acc[mi][ni] = (f32x4){0.f, 0.f, 0.f, 0.f};

    for (int it = 0; it < 8; ++it) {
        const int k0 = it * 128;
        #pragma unroll
        for (int hh = 0; hh < 2; ++hh) {
            const int kh64 = k0 + hh * 64;
            async16(ctxb + (size_t)(m0 + br0) * DD + kh64 + bc0 * 8, &As[hh][ldb]);
            async16(ctxb + (size_t)(m0 + br1) * DD + kh64 + bc1 * 8, &As[hh][ldb + 2048]);
            async16(woT  + (size_t)(n0 + br0) * DD + kh64 + bc0 * 8, &Bs[hh][ldb]);
            async16(woT  + (size_t)(n0 + br1) * DD + kh64 + bc1 * 8, &Bs[hh][ldb + 2048]);
        }
        __syncthreads();
        #pragma unroll
        for (int hh = 0; hh < 2; ++hh) {
            #pragma unroll
            for (int kh = 0; kh < 2; ++kh) {
                bfrag av[2], bv[2];
                #pragma unroll
                for (int mi = 0; mi < 2; ++mi) av[mi] = *(const bfrag*)&As[hh][aoff[mi][kh]];
                #pragma unroll
                for (int ni = 0; ni < 2; ++ni) bv[ni] = *(const bfrag*)&Bs[hh][boff[ni][kh]];
                #pragma unroll
                for (int mi = 0; mi < 2; ++mi)
                    #pragma unroll
                    for (int ni = 0; ni < 2; ++ni)
                        acc[mi][ni] = mfma16(av[mi], bv[ni], acc[mi][ni]);
            }
        }
        __syncthreads();
    }

    float bias[2];
    #pragma unroll
    for (int ni = 0; ni < 2; ++ni)
        bias[ni] = bo[n0 + wn * 32 + ni * 16 + lane15];

    #pragma unroll
    for (int mi = 0; mi < 2; ++mi) {
        #pragma unroll
        for (int r = 0; r < 4; ++r) {
            int m = m0 + wm * 32 + mi * 16 + quad * 4 + r;
            #pragma unroll
            for (int ni = 0; ni < 2; ++ni) {
                int n = n0 + wn * 32 + ni * 16 + lane15;
                out[(size_t)m * DD + n] = acc[mi][ni][r] + bias[ni];
            }
        }
    }
}

// ===========================================================================
// MFMA flash attention — SPLIT-K over kv tiles (no running-max => partials
// are LINEAR: (sum PV, sum P) add across chunks). qt>=16 rows split into
// chunk0 (kt 0..15) + chunk1 (kt 16..qt), each writing fp32 partials; qt<16
// single-chunk writes ctx directly. 1536 blocks sorted longest-first ->
// backfill replaces the no-backfill 32-iter wall (occupancy was 25%).
// Inner loop = round-2 version (best measured).
// ===========================================================================
struct AttnState {
    f32x4 acc_o[4];
    f32x4 acc_s;
};

template<bool MASKED>
__device__ __forceinline__ void qkt_pv(
    const u16* __restrict__ Kc, const u16* __restrict__ Vc,
    const bfrag bq[2], const int koff[2], const int voffb[4],
    bool qhi, int kv0, int qg, int quad4,
    AttnState& st, s16x4 ones4)
{
    f32x4 sT[4];
    #pragma unroll
    for (int ni = 0; ni < 4; ++ni) sT[ni] = (f32x4){0.f, 0.f, 0.f, 0.f};

    bfrag vv[2][4];
    #pragma unroll
    for (int nd = 0; nd < 4; ++nd)
        vv[0][nd] = *(const bfrag*)&Vc[voffb[0] + nd * 1024];

    __builtin_amdgcn_s_setprio(1);
    #pragma unroll
    for (int kh = 0; kh < 2; ++kh)
        #pragma unroll
        for (int ni = 0; ni < 4; ++ni)
            sT[ni] = mfma16(*(const bfrag*)&Kc[koff[kh] + ni * 1024], bq[kh], sT[ni]);
    __builtin_amdgcn_s_setprio(0);

    #pragma unroll
    for (int ni = 0; ni < 4; ++ni) {
        if (ni < 3) {
            #pragma unroll
            for (int nd = 0; nd < 4; ++nd)
                vv[(ni + 1) & 1][nd] = *(const bfrag*)&Vc[voffb[ni + 1] + nd * 1024];
        }
        float pv[4];
        #pragma unroll
        for (int r = 0; r < 4; ++r) {
            float v = sT[ni][r];
            if (MASKED) {
                int kvg = kv0 + ni * 16 + quad4 + r;
                if (kvg > qg) v = NEG_BIG;
            }
            pv[r] = exp2f(v);
        }
        unsigned lo = __builtin_amdgcn_perm(
            __builtin_bit_cast(unsigned, pv[1]),
            __builtin_bit_cast(unsigned, pv[0]), 0x07060302u);
        unsigned hi = __builtin_amdgcn_perm(
            __builtin_bit_cast(unsigned, pv[3]),
            __builtin_bit_cast(unsigned, pv[2]), 0x07060302u);
        s16x4 pf = __builtin_bit_cast(s16x4,
            ((unsigned long long)hi << 32) | (unsigned long long)lo);
        __builtin_amdgcn_s_setprio(1);
        st.acc_s = mfma_pv(ones4, pf, st.acc_s);
        #pragma unroll
        for (int nd = 0; nd < 4; ++nd) {
            bfrag v8 = vv[ni & 1][nd];
            s16x4 vlo = __builtin_shufflevector(v8, v8, 0, 1, 2, 3);
            s16x4 vhi = __builtin_shufflevector(v8, v8, 4, 5, 6, 7);
            s16x4 va = qhi ? vhi : vlo;
            st.acc_o[nd] = mfma_pv(va, pf, st.acc_o[nd]);
        }
        __builtin_amdgcn_s_setprio(0);
    }
}

__global__ __launch_bounds__(256, 4) void attn_k(
    const u16* __restrict__ Q, const u16* __restrict__ K,
    const u16* __restrict__ Vt, u16* __restrict__ ctx,
    float* __restrict__ Pb, float* __restrict__ Sb)
{
    __shared__ __align__(16) u16 Ks[2][64 * 64];   // 16 KB
    __shared__ __align__(16) u16 Vs[2][64 * 64];   // 16 KB
    const int t = threadIdx.x;
    const int lane15 = t & 15, quad = (t >> 4) & 3, wave = t >> 6;

    // task decode: idx = bh + 32*task; tasks sorted longest-first.
    //   task  0..15 : chunk0 of qt=16+task  (kt 0..15, 16 iters)
    //   task 16..31 : chunk1 of qt=31-(task-16) (kt 16..qt, 16..1 iters desc)
    //   task 32..47 : single  qt=15-(task-32)   (kt 0..qt, 16..1 iters desc)
    const int idx = (int)blockIdx.x;
    const int bh = idx & 31;
    const int task = idx >> 5;
    int qt, k0, k1, slot = 0;
    if (task < 16)      { qt = 16 + task;        k0 = 0;  k1 = 16;
                          slot = (bh * 16 + task) * 2; }
    else if (task < 32) { qt = 31 - (task - 16); k0 = 16; k1 = qt + 1;
                          slot = (bh * 16 + (qt - 16)) * 2 + 1; }
    else                { qt = 15 - (task - 32); k0 = 0;  k1 = qt + 1; }

    const int q0 = qt * 64;
    const int b = bh >> 4, h = bh & 15;
    const u16* Qb = Q  + (size_t)bh * SS * HDIM;
    const u16* Kb = K  + (size_t)bh * SS * HDIM;
    const u16* Vb = Vt + (size_t)bh * HDIM * SS;

    const int kr0 = t >> 3,         ks0 = t & 7;
    const int kr1 = (t + 256) >> 3, ks1 = (t + 256) & 7;
    const int kc0 = ks0 ^ (kr0 & 7);
    const int kc1 = ks1 ^ (kr1 & 7);
    const int ldst = (t & 192) * 8;

    // Q staged temporarily into Ks[1]; K/V tile k0 into buffer 0 (k0 even).
    async16(Qb + (size_t)(q0 + kr0) * HDIM + kc0 * 8, &Ks[1][ldst]);
    async16(Qb + (size_t)(q0 + kr1) * HDIM + kc1 * 8, &Ks[1][ldst + 2048]);
    async16(Kb + (size_t)(k0 * 64 + kr0) * HDIM + kc0 * 8, &Ks[0][ldst]);
    async16(Kb + (size_t)(k0 * 64 + kr1) * HDIM + kc1 * 8, &Ks[0][ldst + 2048]);
    async16(Vb + (size_t)kr0 * SS + k0 * 64 + kc0 * 8, &Vs[0][ldst]);
    async16(Vb + (size_t)kr1 * SS + k0 * 64 + kc1 * 8, &Vs[0][ldst + 2048]);

    const int r7 = lane15 & 7;
    int koff[2];
    #pragma unroll
    for (int kh = 0; kh < 2; ++kh)
        koff[kh] = (lane15 * 8 + ((kh * 4 + quad) ^ r7)) * 8;
    int voffb[4];
    #pragma unroll
    for (int ni = 0; ni < 4; ++ni)
        voffb[ni] = (lane15 * 8 + ((ni * 2 + (quad >> 1)) ^ r7)) * 8;
    const bool qhi = (quad & 1) != 0;

    __syncthreads();
    bfrag bq[2];
    bq[0] = *(const bfrag*)&Ks[1][koff[0] + wave * 1024];
    bq[1] = *(const bfrag*)&Ks[1][koff[1] + wave * 1024];
    __syncthreads();   // Q reads done before first prefetch overwrites Ks[1]

    s16x4 ones4;
    #pragma unroll
    for (int i = 0; i < 4; ++i) ones4[i] = (short)0x3f80;   // bf16 1.0

    AttnState st;
    st.acc_s = (f32x4){0.f, 0.f, 0.f, 0.f};
    #pragma unroll
    for (int nd = 0; nd < 4; ++nd) st.acc_o[nd] = (f32x4){0.f, 0.f, 0.f, 0.f};

    const int qg = q0 + wave * 16 + lane15;
    const int quad4 = quad * 4;

    for (int kt = k0; kt < k1 - 1; ++kt) {
        const int nv0 = (kt + 1) * 64;
        const int pbuf = (kt + 1) & 1;
        async16(Kb + (size_t)(nv0 + kr0) * HDIM + kc0 * 8, &Ks[pbuf][ldst]);
        async16(Kb + (size_t)(nv0 + kr1) * HDIM + kc1 * 8, &Ks[pbuf][ldst + 2048]);
        async16(Vb + (size_t)kr0 * SS + nv0 + kc0 * 8, &Vs[pbuf][ldst]);
        async16(Vb + (size_t)kr1 * SS + nv0 + kc1 * 8, &Vs[pbuf][ldst + 2048]);
        qkt_pv<false>(Ks[kt & 1], Vs[kt & 1], bq, koff, voffb,
                      qhi, kt * 64, qg, quad4, st, ones4);
        __syncthreads();
    }
    // final tile of this chunk: masked iff it is the diagonal
    {
        const int kt = k1 - 1;
        if (kt == qt)
            qkt_pv<true>(Ks[kt & 1], Vs[kt & 1], bq, koff, voffb,
                         qhi, kt * 64, qg, quad4, st, ones4);
        else
            qkt_pv<false>(Ks[kt & 1], Vs[kt & 1], bq, koff, voffb,
                          qhi, kt * 64, qg, quad4, st, ones4);
    }

    if (task < 32) {
        // partial write: fp32 numerator tile [64 q][64 d] + row sums
        float* P = Pb + (size_t)slot * 4096;
        float* S = Sb + (size_t)slot * 64;
        const int q = wave * 16 + lane15;
        if (quad == 0) S[q] = st.acc_s[0];
        #pragma unroll
        for (int nd = 0; nd < 4; ++nd) {
            float4 v = {st.acc_o[nd][0], st.acc_o[nd][1],
                        st.acc_o[nd][2], st.acc_o[nd][3]};
            *(float4*)(P + q * 64 + nd * 16 + quad4) = v;
        }
    } else {
        const float inv = 1.f / st.acc_s[0];
        const int srow = q0 + wave * 16 + lane15;
        u16* dst = ctx + ((size_t)b * SS + srow) * DD + h * HDIM + quad4;
        #pragma unroll
        for (int nd = 0; nd < 4; ++nd) {
            uint2 stw;
            stw.x = (unsigned)f2u(st.acc_o[nd][0] * inv) |
                    ((unsigned)f2u(st.acc_o[nd][1] * inv) << 16);
            stw.y = (unsigned)f2u(st.acc_o[nd][2] * inv) |
                    ((unsigned)f2u(st.acc_o[nd][3] * inv) << 16);
            *(uint2*)(dst + nd * 16) = stw;
        }
    }
}

// ---------------------------------------------------------------------------
// combine: for qt>=16, ctx = (P0+P1) / (S0+S1), bf16. 512 blocks.
// ---------------------------------------------------------------------------
__global__ __launch_bounds__(256) void combine_k(
    const float* __restrict__ Pb, const float* __restrict__ Sb,
    u16* __restrict__ ctx)
{
    const int idx = (int)blockIdx.x;      // bh*16 + (qt-16)
    const int bh = idx >> 4, qtl = idx & 15;
    const int qt = 16 + qtl;
    const int b = bh >> 4, h = bh & 15;
    const int t = threadIdx.x;
    const int row = t >> 2, cq = (t & 3) * 16;

    const size_t s0 = (size_t)idx * 2;
    const float* P0 = Pb + s0 * 4096;
    const float* P1 = P0 + 4096;
    const float inv = 1.f / (Sb[s0 * 64 + row] + Sb[(s0 + 1) * 64 + row]);

    u16 o[16];
    #pragma unroll
    for (int j = 0; j < 4; ++j) {
        float4 a  = *(const float4*)(P0 + row * 64 + cq + j * 4);
        float4 b4 = *(const float4*)(P1 + row * 64 + cq + j * 4);
        o[j*4+0] = f2u((a.x + b4.x) * inv);
        o[j*4+1] = f2u((a.y + b4.y) * inv);
        o[j*4+2] = f2u((a.z + b4.z) * inv);
        o[j*4+3] = f2u((a.w + b4.w) * inv);
    }
    u16* dst = ctx + ((size_t)b * SS + qt * 64 + row) * DD + h * HDIM + cq;
    *(uint4*)(dst)     = ((uint4*)o)[0];
    *(uint4*)(dst + 8) = ((uint4*)o)[1];
}

extern "C" void kernel_launch(void* const* d_in, const int* in_sizes, int n_in,
                              void* d_out, int out_size, void* d_ws, size_t ws_size,
                              hipStream_t stream) {
    const float* x  = (const float*)d_in[0];
    const float* wq = (const float*)d_in[1];
    const float* wk = (const float*)d_in[2];
    const float* wv = (const float*)d_in[3];
    const float* wo = (const float*)d_in[4];
    const float* bo = (const float*)d_in[5];
    float* out = (float*)d_out;

    char* ws = (char*)d_ws;
    const size_t MB = (size_t)1024 * 1024;
    u16* xb  = (u16*)(ws);                 // 8MB; ctx reuses after qkv
    u16* wT  = (u16*)(ws + 8 * MB);        // 8MB
    u16* Qb  = (u16*)(ws + 16 * MB);       // 8MB
    u16* Kb  = (u16*)(ws + 24 * MB);       // 8MB
    u16* Vt  = (u16*)(ws + 32 * MB);       // 8MB
    float* Pb = (float*)(ws + 40 * MB);    // 16MB fp32 partial numerators
    float* Sb = (float*)(ws + 56 * MB);    // 256KB fp32 partial row-sums
    u16* ctxb = xb;

    prep_k    <<<3072, 256, 0, stream>>>(x, xb, wq, wk, wv, wo, wT);
    gemm_qkv_k<<<dim3(32, 16, 3), 256, 0, stream>>>(xb, wT, Qb, Kb, Vt);
    attn_k    <<<1536, 256, 0, stream>>>(Qb, Kb, Vt, ctxb, Pb, Sb);
    combine_k <<<512, 256, 0, stream>>>(Pb, Sb, ctxb);
    gemm_out_k<<<dim3(64, 16), 256, 0, stream>>>(ctxb, wT + (size_t)3 * DD * DD, bo, out);
}

// Round 6
// 169.600 us; speedup vs baseline: 1.1116x; 1.0717x over previous
//
#include <hip/hip_runtime.h>
#include <hip/hip_bf16.h>
#include <math.h>

#define BB 2
#define SS 2048
#define DD 1024
#define HH 16
#define HDIM 64

typedef unsigned short u16;
typedef __attribute__((ext_vector_type(8))) short bfrag;   // 8 bf16 = 4 VGPRs
typedef __attribute__((ext_vector_type(4))) short s16x4;   // 4 bf16 = 2 VGPRs
typedef __attribute__((ext_vector_type(4))) float f32x4;

#define NEG_BIG (-1e30f)
// 1/sqrt(64) * log2(e): folded into Q so attention uses exp2 directly
#define QSCALE 0.18033688011112042f

__device__ __forceinline__ u16 f2u(float f) {
    unsigned int u = __builtin_bit_cast(unsigned int, f);
    u += 0x7fffu + ((u >> 16) & 1u);
    return (u16)(u >> 16);
}

__device__ __forceinline__ float fexp2(float x) {
#if __has_builtin(__builtin_amdgcn_exp2f)
    return __builtin_amdgcn_exp2f(x);   // raw v_exp_f32 (TRANS pipe, 1 instr)
#else
    return exp2f(x);
#endif
}

__device__ __forceinline__ void async16(const u16* g, u16* l) {
    __builtin_amdgcn_global_load_lds((__attribute__((address_space(1))) void*)g,
                                     (__attribute__((address_space(3))) void*)l,
                                     16, 0, 0);
}

__device__ __forceinline__ f32x4 mfma16(bfrag a, bfrag b, f32x4 c) {
    return __builtin_amdgcn_mfma_f32_16x16x32_bf16(a, b, c, 0, 0, 0);
}

// 16x16x16 bf16 MFMA: builtin name differs across ROCm; dispatch at compile time.
__device__ __forceinline__ f32x4 mfma_pv(s16x4 a, s16x4 b, f32x4 c) {
#if __has_builtin(__builtin_amdgcn_mfma_f32_16x16x16_bf16)
    return __builtin_amdgcn_mfma_f32_16x16x16_bf16(a, b, c, 0, 0, 0);
#elif __has_builtin(__builtin_amdgcn_mfma_f32_16x16x16bf16_1k)
    return __builtin_amdgcn_mfma_f32_16x16x16bf16_1k(a, b, c, 0, 0, 0);
#else
    f32x4 d;
    asm("v_mfma_f32_16x16x16_bf16 %0, %1, %2, %3" : "=v"(d) : "v"(a), "v"(b), "v"(c));
    return d;
#endif
}

// ---------------------------------------------------------------------------
// prep: fused cvt_x + cvt_wT (round-0 verbatim).
// ---------------------------------------------------------------------------
__global__ __launch_bounds__(256) void prep_k(
    const float* __restrict__ x,  u16* __restrict__ xb,
    const float* __restrict__ wq, const float* __restrict__ wk,
    const float* __restrict__ wv, const float* __restrict__ wo,
    u16* __restrict__ wT)
{
    const int id = blockIdx.x;
    const int t = threadIdx.x;
    if (id < 2048) {
        int i = (id * 256 + t) * 8;
        float4 a = *(const float4*)(x + i);
        float4 b = *(const float4*)(x + i + 4);
        u16 o[8] = { f2u(a.x), f2u(a.y), f2u(a.z), f2u(a.w),
                     f2u(b.x), f2u(b.y), f2u(b.z), f2u(b.w) };
        *(uint4*)(xb + i) = *(uint4*)o;
        return;
    }
    const int wid = id - 2048;
    const int z = wid >> 8;
    const int kt = wid & 15, nt = (wid >> 4) & 15;
    const float* w = (z == 0) ? wq : (z == 1) ? wk : (z == 2) ? wv : wo;
    u16* o = wT + (size_t)z * DD * DD;
    __shared__ __align__(16) u16 T[64][72];
    const int k0 = kt * 64, n0 = nt * 64;
    {
        int kr = t >> 2, nb = (t & 3) * 16;
        const float4* s4 = (const float4*)(w + (size_t)(k0 + kr) * DD + n0 + nb);
        #pragma unroll
        for (int jj = 0; jj < 4; ++jj) {
            float4 v = s4[jj];
            T[kr][nb + jj*4 + 0] = f2u(v.x);
            T[kr][nb + jj*4 + 1] = f2u(v.y);
            T[kr][nb + jj*4 + 2] = f2u(v.z);
            T[kr][nb + jj*4 + 3] = f2u(v.w);
        }
    }
    __syncthreads();
    {
        int nr = t >> 2, kb = (t & 3) * 16;
        u16 tmp[16];
        #pragma unroll
        for (int j = 0; j < 16; ++j) tmp[j] = T[kb + j][nr];
        *(uint4*)(o + (size_t)(n0 + nr) * DD + k0 + kb)     = ((uint4*)tmp)[0];
        *(uint4*)(o + (size_t)(n0 + nr) * DD + k0 + kb + 8) = ((uint4*)tmp)[1];
    }
}

// ===========================================================================
// QKV GEMM (round-0 verbatim): BM=128, BN=64, BK=64 -> 1536 blocks.
// ===========================================================================
__global__ __launch_bounds__(256) void gemm_qkv_k(
    const u16* __restrict__ xb, const u16* __restrict__ wT,
    u16* __restrict__ Qo, u16* __restrict__ Ko, u16* __restrict__ Vt)
{
    const u16* wTz = wT + (size_t)blockIdx.z * DD * DD;
    const float osc = (blockIdx.z == 0) ? QSCALE : 1.0f;

    __shared__ __align__(16) u16 As[128 * 64];   // 16 KB
    __shared__ __align__(16) u16 Bs[64 * 64];    // 8 KB

    const int t = threadIdx.x;
    const int m0 = blockIdx.x * 128, n0 = blockIdx.y * 64;
    const int lane15 = t & 15, quad = (t >> 4) & 3, wave = t >> 6;
    const int wm = wave & 1, wn = wave >> 1;

    int arow[4], acol[4];
    #pragma unroll
    for (int i = 0; i < 4; ++i) {
        int c = t + i * 256;
        arow[i] = c >> 3;
        acol[i] = (c & 7) ^ (arow[i] & 7);
    }
    const int br0 = t >> 3,         bs0 = t & 7;
    const int br1 = (t + 256) >> 3, bs1 = (t + 256) & 7;
    const int bc0 = bs0 ^ (br0 & 7);
    const int bc1 = bs1 ^ (br1 & 7);
    const int ldb = (t & 192) * 8;

    int aoff[4][2], boff[2][2];
    #pragma unroll
    for (int mi = 0; mi < 4; ++mi) {
        int r = wm * 64 + mi * 16 + lane15;
        #pragma unroll
        for (int kh = 0; kh < 2; ++kh)
            aoff[mi][kh] = (r * 8 + ((kh * 4 + quad) ^ (r & 7))) * 8;
    }
    #pragma unroll
    for (int ni = 0; ni < 2; ++ni) {
        int r = wn * 32 + ni * 16 + lane15;
        #pragma unroll
        for (int kh = 0; kh < 2; ++kh)
            boff[ni][kh] = (r * 8 + ((kh * 4 + quad) ^ (r & 7))) * 8;
    }

    f32x4 acc[4][2];
    #pragma unroll
    for (int mi = 0; mi < 4; ++mi)
        #pragma unroll
        for (int ni = 0; ni < 2; ++ni)
            acc[mi][ni] = (f32x4){0.f, 0.f, 0.f, 0.f};

    for (int it = 0; it < 16; ++it) {
        const int k0 = it * 64;
        #pragma unroll
        for (int i = 0; i < 4; ++i)
            async16(xb + (size_t)(m0 + arow[i]) * DD + k0 + acol[i] * 8,
                    As + ldb + i * 2048);
        async16(wTz + (size_t)(n0 + br0) * DD + k0 + bc0 * 8, Bs + ldb);
        async16(wTz + (size_t)(n0 + br1) * DD + k0 + bc1 * 8, Bs + ldb + 2048);
        __syncthreads();
        #pragma unroll
        for (int kh = 0; kh < 2; ++kh) {
            bfrag av[4], bv[2];
            #pragma unroll
            for (int mi = 0; mi < 4; ++mi) av[mi] = *(const bfrag*)(As + aoff[mi][kh]);
            #pragma unroll
            for (int ni = 0; ni < 2; ++ni) bv[ni] = *(const bfrag*)(Bs + boff[ni][kh]);
            #pragma unroll
            for (int mi = 0; mi < 4; ++mi)
                #pragma unroll
                for (int ni = 0; ni < 2; ++ni)
                    acc[mi][ni] = mfma16(av[mi], bv[ni], acc[mi][ni]);
        }
        __syncthreads();
    }

    const int h = n0 >> 6;
    const int bq = m0 >> 11;
    const int ms = m0 & (SS - 1);

    if (blockIdx.z != 2) {
        u16* out = (blockIdx.z == 0) ? Qo : Ko;
        u16* dst = out + (((size_t)(bq * HH + h)) * SS) * HDIM;
        #pragma unroll
        for (int mi = 0; mi < 4; ++mi) {
            #pragma unroll
            for (int r = 0; r < 4; ++r) {
                int s = ms + wm * 64 + mi * 16 + quad * 4 + r;
                #pragma unroll
                for (int ni = 0; ni < 2; ++ni) {
                    int hd = wn * 32 + ni * 16 + lane15;
                    dst[(size_t)s * HDIM + hd] = f2u(acc[mi][ni][r] * osc);
                }
            }
        }
    } else {
        u16* T = As;
        __syncthreads();
        #pragma unroll
        for (int mi = 0; mi < 4; ++mi)
            #pragma unroll
            for (int r = 0; r < 4; ++r) {
                int ml = wm * 64 + mi * 16 + quad * 4 + r;
                #pragma unroll
                for (int ni = 0; ni < 2; ++ni) {
                    int nl = wn * 32 + ni * 16 + lane15;
                    T[nl * 128 + (ml ^ ((nl & 7) << 4))] = f2u(acc[mi][ni][r]);
                }
            }
        __syncthreads();
        u16* dst = Vt + ((size_t)(bq * HH + h)) * (HDIM * SS);
        #pragma unroll
        for (int i = 0; i < 4; ++i) {
            int c = t + i * 256;
            int row = c >> 4;
            int mb  = (c & 15) * 8;
            uint4 val = *(const uint4*)&T[row * 128 + (mb ^ ((row & 7) << 4))];
            *(uint4*)(dst + (size_t)row * SS + ms + mb) = val;
        }
    }
}

// ---------------------------------------------------------------------------
// Out projection (round-0 verbatim): BM=64, BN=64, BK=128 -> grid (64,16).
// ---------------------------------------------------------------------------
__global__ __launch_bounds__(256) void gemm_out_k(
    const u16* __restrict__ ctxb, const u16* __restrict__ woT,
    const float* __restrict__ bo, float* __restrict__ out)
{
    __shared__ __align__(16) u16 As[2][4096];    // [k-half][64x64]
    __shared__ __align__(16) u16 Bs[2][4096];

    const int t = threadIdx.x;
    const int m0 = blockIdx.x * 64, n0 = blockIdx.y * 64;
    const int lane15 = t & 15, quad = (t >> 4) & 3, wave = t >> 6;
    const int wm = wave & 1, wn = wave >> 1;

    const int br0 = t >> 3,         bs0 = t & 7;
    const int br1 = (t + 256) >> 3, bs1 = (t + 256) & 7;
    const int bc0 = bs0 ^ (br0 & 7);
    const int bc1 = bs1 ^ (br1 & 7);
    const int ldb = (t & 192) * 8;

    int aoff[2][2], boff[2][2];
    #pragma unroll
    for (int mi = 0; mi < 2; ++mi) {
        int r = wm * 32 + mi * 16 + lane15;
        #pragma unroll
        for (int kh = 0; kh < 2; ++kh)
            aoff[mi][kh] = (r * 8 + ((kh * 4 + quad) ^ (r & 7))) * 8;
    }
    #pragma unroll
    for (int ni = 0; ni < 2; ++ni) {
        int r = wn * 32 + ni * 16 + lane15;
        #pragma unroll
        for (int kh = 0; kh < 2; ++kh)
            boff[ni][kh] = (r * 8 + ((kh * 4 + quad) ^ (r & 7))) * 8;
    }

    f32x4 acc[2][2];
    #pragma unroll
    for (int mi = 0; mi < 2; ++mi)
        #pragma unroll
        for (int ni = 0; ni < 2; ++ni)
            acc[mi][ni] = (f32x4){0.f, 0.f, 0.f, 0.f};

    for (int it = 0; it < 8; ++it) {
        const int k0 = it * 128;
        #pragma unroll
        for (int hh = 0; hh < 2; ++hh) {
            const int kh64 = k0 + hh * 64;
            async16(ctxb + (size_t)(m0 + br0) * DD + kh64 + bc0 * 8, &As[hh][ldb]);
            async16(ctxb + (size_t)(m0 + br1) * DD + kh64 + bc1 * 8, &As[hh][ldb + 2048]);
            async16(woT  + (size_t)(n0 + br0) * DD + kh64 + bc0 * 8, &Bs[hh][ldb]);
            async16(woT  + (size_t)(n0 + br1) * DD + kh64 + bc1 * 8, &Bs[hh][ldb + 2048]);
        }
        __syncthreads();
        #pragma unroll
        for (int hh = 0; hh < 2; ++hh) {
            #pragma unroll
            for (int kh = 0; kh < 2; ++kh) {
                bfrag av[2], bv[2];
                #pragma unroll
                for (int mi = 0; mi < 2; ++mi) av[mi] = *(const bfrag*)&As[hh][aoff[mi][kh]];
                #pragma unroll
                for (int ni = 0; ni < 2; ++ni) bv[ni] = *(const bfrag*)&Bs[hh][boff[ni][kh]];
                #pragma unroll
                for (int mi = 0; mi < 2; ++mi)
                    #pragma unroll
                    for (int ni = 0; ni < 2; ++ni)
                        acc[mi][ni] = mfma16(av[mi], bv[ni], acc[mi][ni]);
            }
        }
        __syncthreads();
    }

    float bias[2];
    #pragma unroll
    for (int ni = 0; ni < 2; ++ni)
        bias[ni] = bo[n0 + wn * 32 + ni * 16 + lane15];

    #pragma unroll
    for (int mi = 0; mi < 2; ++mi) {
        #pragma unroll
        for (int r = 0; r < 4; ++r) {
            int m = m0 + wm * 32 + mi * 16 + quad * 4 + r;
            #pragma unroll
            for (int ni = 0; ni < 2; ++ni) {
                int n = n0 + wn * 32 + ni * 16 + lane15;
                out[(size_t)m * DD + n] = acc[mi][ni][r] + bias[ni];
            }
        }
    }
}

// ===========================================================================
// MFMA flash attention — r2 schedule (best measured), VALU-cut inner loop:
// raw v_exp_f32 (no libm fixup), direct b64 V reads (no half-select
// cndmasks, no reg double-buffer), strength-reduced staging pointers.
// ===========================================================================
template<bool MASKED>
__device__ __forceinline__ void qkt_pv(
    const u16* __restrict__ Kc, const u16* __restrict__ Vc,
    const bfrag bq[2], const int koff[2], const int voff[4],
    int kv0, int qg, int quad4, f32x4 acc_o[4], f32x4& acc_s, s16x4 ones4)
{
    f32x4 sT[4];
    #pragma unroll
    for (int ni = 0; ni < 4; ++ni) sT[ni] = (f32x4){0.f, 0.f, 0.f, 0.f};

    __builtin_amdgcn_s_setprio(1);
    #pragma unroll
    for (int kh = 0; kh < 2; ++kh)
        #pragma unroll
        for (int ni = 0; ni < 4; ++ni)
            sT[ni] = mfma16(*(const bfrag*)&Kc[koff[kh] + ni * 1024], bq[kh], sT[ni]);
    __builtin_amdgcn_s_setprio(0);

    #pragma unroll
    for (int ni = 0; ni < 4; ++ni) {
        float pv[4];
        #pragma unroll
        for (int r = 0; r < 4; ++r) {
            float v = sT[ni][r];
            if (MASKED) {
                int kvg = kv0 + ni * 16 + quad4 + r;
                if (kvg > qg) v = NEG_BIG;
            }
            pv[r] = fexp2(v);
        }
        unsigned lo = __builtin_amdgcn_perm(
            __builtin_bit_cast(unsigned, pv[1]),
            __builtin_bit_cast(unsigned, pv[0]), 0x07060302u);
        unsigned hi = __builtin_amdgcn_perm(
            __builtin_bit_cast(unsigned, pv[3]),
            __builtin_bit_cast(unsigned, pv[2]), 0x07060302u);
        s16x4 pf = __builtin_bit_cast(s16x4,
            ((unsigned long long)hi << 32) | (unsigned long long)lo);
        __builtin_amdgcn_s_setprio(1);
        acc_s = mfma_pv(ones4, pf, acc_s);
        #pragma unroll
        for (int nd = 0; nd < 4; ++nd)
            acc_o[nd] = mfma_pv(*(const s16x4*)&Vc[voff[ni] + nd * 1024],
                                pf, acc_o[nd]);
        __builtin_amdgcn_s_setprio(0);
    }
}

__global__ __launch_bounds__(256, 5) void attn_k(
    const u16* __restrict__ Q, const u16* __restrict__ K,
    const u16* __restrict__ Vt, u16* __restrict__ ctx)
{
    __shared__ __align__(16) u16 Ks[2][64 * 64];   // 16 KB
    __shared__ __align__(16) u16 Vs[2][64 * 64];   // 16 KB
    const int t = threadIdx.x;
    const int lane15 = t & 15, quad = (t >> 4) & 3, wave = t >> 6;
    const int bh = blockIdx.x;
    // balanced causal mapping: dispatch rounds (y&7 fixed) get qt
    // {31-y0, y0, 23-y0, 8+y0} -> per-CU work sum is constant.
    const int yy = (int)blockIdx.y;
    const int y0 = yy & 7, rnd = yy >> 3;
    const int qt = (rnd == 0) ? 31 - y0 : (rnd == 1) ? y0
                 : (rnd == 2) ? 23 - y0 : 8 + y0;
    const int q0 = qt * 64;
    const int b = bh >> 4, h = bh & 15;
    const u16* Qb = Q  + (size_t)bh * SS * HDIM;
    const u16* Kb = K  + (size_t)bh * SS * HDIM;
    const u16* Vb = Vt + (size_t)bh * HDIM * SS;

    // staging map (same swizzle as before)
    const int kr0 = t >> 3,         ks0 = t & 7;
    const int kr1 = (t + 256) >> 3, ks1 = (t + 256) & 7;
    const int kc0 = ks0 ^ (kr0 & 7);
    const int kc1 = ks1 ^ (kr1 & 7);
    const int ldst = (t & 192) * 8;

    // per-thread global staging pointers (strength-reduced in the loop)
    const u16* kga = Kb + (size_t)kr0 * HDIM + kc0 * 8;
    const u16* kgb = Kb + (size_t)kr1 * HDIM + kc1 * 8;
    const u16* vga = Vb + (size_t)kr0 * SS + kc0 * 8;
    const u16* vgb = Vb + (size_t)kr1 * SS + kc1 * 8;

    // Q staged temporarily into Ks[1] (consumed into regs before kt=0 prefetch)
    async16(Qb + (size_t)(q0 + kr0) * HDIM + kc0 * 8, &Ks[1][ldst]);
    async16(Qb + (size_t)(q0 + kr1) * HDIM + kc1 * 8, &Ks[1][ldst + 2048]);
    async16(kga, &Ks[0][ldst]);
    async16(kgb, &Ks[0][ldst + 2048]);
    async16(vga, &Vs[0][ldst]);
    async16(vgb, &Vs[0][ldst + 2048]);

    const int r7 = lane15 & 7;
    // K fragment offsets (row = ni*16+lane15; row&7 == lane15&7): +ni*1024 u16
    int koff[2];
    #pragma unroll
    for (int kh = 0; kh < 2; ++kh)
        koff[kh] = (lane15 * 8 + ((kh * 4 + quad) ^ r7)) * 8;
    // V^T b64 fragment offsets (direct; conflicts proven insensitive)
    int voff[4];
    #pragma unroll
    for (int ni = 0; ni < 4; ++ni)
        voff[ni] = (lane15 * 8 + ((ni * 2 + (quad >> 1)) ^ r7)) * 8 + (quad & 1) * 4;

    __syncthreads();
    bfrag bq[2];
    bq[0] = *(const bfrag*)&Ks[1][koff[0] + wave * 1024];
    bq[1] = *(const bfrag*)&Ks[1][koff[1] + wave * 1024];
    __syncthreads();   // Q reads done before kt=0 prefetch overwrites Ks[1]

    s16x4 ones4;
    #pragma unroll
    for (int i = 0; i < 4; ++i) ones4[i] = (short)0x3f80;   // bf16 1.0

    f32x4 acc_o[4];
    f32x4 acc_s = (f32x4){0.f, 0.f, 0.f, 0.f};
    #pragma unroll
    for (int nd = 0; nd < 4; ++nd) acc_o[nd] = (f32x4){0.f, 0.f, 0.f, 0.f};

    const int qg = q0 + wave * 16 + lane15;   // this lane's absolute q row
    const int quad4 = quad * 4;

    // running prefetch pointers (tile kt+1)
    const u16* kpa = kga + 64 * HDIM;
    const u16* kpb = kgb + 64 * HDIM;
    const u16* vpa = vga + 64;
    const u16* vpb = vgb + 64;

    // off-diagonal tiles: no masking code at all
    for (int kt = 0; kt < qt; ++kt) {
        const int pb = (kt + 1) & 1;
        async16(kpa, &Ks[pb][ldst]);
        async16(kpb, &Ks[pb][ldst + 2048]);
        async16(vpa, &Vs[pb][ldst]);
        async16(vpb, &Vs[pb][ldst + 2048]);
        kpa += 64 * HDIM; kpb += 64 * HDIM;
        vpa += 64;        vpb += 64;
        qkt_pv<false>(Ks[kt & 1], Vs[kt & 1], bq, koff, voff,
                      kt * 64, qg, quad4, acc_o, acc_s, ones4);
        __syncthreads();
    }
    // diagonal tile (no prefetch, masked)
    qkt_pv<true>(Ks[qt & 1], Vs[qt & 1], bq, koff, voff,
                 qt * 64, qg, quad4, acc_o, acc_s, ones4);

    // epilogue: each lane owns one q row; acc_s rows are replicated row-sums
    const float inv = 1.f / acc_s[0];
    const int srow = q0 + wave * 16 + lane15;
    u16* dst = ctx + ((size_t)b * SS + srow) * DD + h * HDIM + quad4;
    #pragma unroll
    for (int nd = 0; nd < 4; ++nd) {
        uint2 stw;
        stw.x = (unsigned)f2u(acc_o[nd][0] * inv) |
                ((unsigned)f2u(acc_o[nd][1] * inv) << 16);
        stw.y = (unsigned)f2u(acc_o[nd][2] * inv) |
                ((unsigned)f2u(acc_o[nd][3] * inv) << 16);
        *(uint2*)(dst + nd * 16) = stw;
    }
}

extern "C" void kernel_launch(void* const* d_in, const int* in_sizes, int n_in,
                              void* d_out, int out_size, void* d_ws, size_t ws_size,
                              hipStream_t stream) {
    const float* x  = (const float*)d_in[0];
    const float* wq = (const float*)d_in[1];
    const float* wk = (const float*)d_in[2];
    const float* wv = (const float*)d_in[3];
    const float* wo = (const float*)d_in[4];
    const float* bo = (const float*)d_in[5];
    float* out = (float*)d_out;

    char* ws = (char*)d_ws;
    const size_t MB8 = (size_t)8 * 1024 * 1024;
    u16* xb  = (u16*)(ws);             // 8MB; ctx reuses after qkv consumption
    u16* wT  = (u16*)(ws + MB8);       // 8MB
    u16* Qb  = (u16*)(ws + 2 * MB8);   // 8MB
    u16* Kb  = (u16*)(ws + 3 * MB8);   // 8MB
    u16* Vt  = (u16*)(ws + 4 * MB8);   // 8MB
    u16* ctxb = xb;

    prep_k    <<<3072, 256, 0, stream>>>(x, xb, wq, wk, wv, wo, wT);
    gemm_qkv_k<<<dim3(32, 16, 3), 256, 0, stream>>>(xb, wT, Qb, Kb, Vt);
    attn_k    <<<dim3(32, 32), 256, 0, stream>>>(Qb, Kb, Vt, ctxb);
    gemm_out_k<<<dim3(64, 16), 256, 0, stream>>>(ctxb, wT + (size_t)3 * DD * DD, bo, out);
}